// Round 15
// baseline (170.721 us; speedup 1.0000x reference)
//
#include <hip/hip_runtime.h>

#define TT 8192
#define CIN 512
#define COUT 512
#define NB 8
#define KTOT 1536   // 3 * CIN
#define NT 24       // K tiles of 64

typedef __attribute__((ext_vector_type(4))) float f32x4;
typedef __attribute__((ext_vector_type(8))) short bf16x8;

#define GLD16(g, l) __builtin_amdgcn_global_load_lds(                      \
    (const __attribute__((address_space(1))) void*)(g),                    \
    (__attribute__((address_space(3))) void*)(l), 16, 0, 0)

#define CFENCE() asm volatile("" ::: "memory")
#define SBAR() do { CFENCE(); __builtin_amdgcn_s_barrier(); CFENCE(); } while (0)
#define VMCNT6() asm volatile("s_waitcnt vmcnt(6)" ::: "memory")
#define VMCNT2() asm volatile("s_waitcnt vmcnt(2)" ::: "memory")
#define VMCNT0() asm volatile("s_waitcnt vmcnt(0)" ::: "memory")
#define LGKM0() asm volatile("s_waitcnt lgkmcnt(0)" ::: "memory")
#define MFMA(a_, b_, c_) __builtin_amdgcn_mfma_f32_16x16x32_bf16((a_), (b_), (c_), 0, 0, 0)

__device__ inline unsigned short f2bf(float f) {
  union { float f; unsigned int u; } v; v.f = f;
  unsigned int u = v.u;
  unsigned int r = (u + 0x7FFFu + ((u >> 16) & 1u)) >> 16;  // RNE
  return (unsigned short)r;
}

__global__ void k_convert_w(const float* __restrict__ W0, const float* __restrict__ W1,
                            const float* __restrict__ W2, unsigned short* __restrict__ Wb) {
  int i = blockIdx.x * 256 + threadIdx.x;
  if (i >= COUT * CIN) return;
  const float* Ws = blockIdx.y == 0 ? W0 : (blockIdx.y == 1 ? W1 : W2);
  int o = i >> 9, c = i & 511;
  Wb[(size_t)o * KTOT + blockIdx.y * CIN + c] = f2bf(Ws[i]);
}

// x (B, C, T) fp32 -> xbT (T, C) bf16 per batch. grid (T/64, C/64, nb), block 256
__global__ void k_transpose(const float* __restrict__ x, unsigned short* __restrict__ xbT,
                            int b_base) {
  int b = b_base + blockIdx.z;
  const float* xb = x + (size_t)b * CIN * TT;
  unsigned short* xo = xbT + (size_t)blockIdx.z * TT * CIN;
  __shared__ float tile[64][65];
  int t0 = blockIdx.x * 64, c0 = blockIdx.y * 64;
  int tid = threadIdx.x;
#pragma unroll
  for (int it = 0; it < 16; ++it) {
    int L = it * 256 + tid;
    int c = L >> 6, t = L & 63;
    tile[c][t] = xb[(size_t)(c0 + c) * TT + (t0 + t)];
  }
  __syncthreads();
#pragma unroll
  for (int it = 0; it < 16; ++it) {
    int L = it * 256 + tid;
    int t = L >> 6, c = L & 63;
    xo[(size_t)(t0 + t) * CIN + (c0 + c)] = f2bf(tile[c][t]);
  }
}

// -------- 256x256 fused gather-GEMM, half-publish pipeline (2 barriers/tile) --------
// grid (8, 64), block 512 (8 waves, 2M x 4N). id%8 = batch -> XCD.
// Tile t: PH0{read af(mh0)+bf0+bf1; stage B(t+1)+A-g0(t+1); MFMA Q00+Q01
//             (compiler partial-lgkm overlaps tail reads); vmcnt(6); BAR=pub A-mh1(t)}
//         PH2{read af(mh1); stage A-g1(t+1); MFMA Q10+Q11;
//             lgkm0; vmcnt(2) [drain B+A-g0(t+1), keep A-g1(t+1)]; BAR}
// MID lgkm0 removed: only the END lgkm0 fences the WAR (t+1 PH0 staging into cur).
__global__ __launch_bounds__(512) void k_gemm256(
    const unsigned short* __restrict__ Wb, const unsigned short* __restrict__ xbT,
    const float* __restrict__ d, const float* __restrict__ bias,
    float* __restrict__ out) {
  __shared__ __align__(16) unsigned short As[2][256 * 64];
  __shared__ __align__(16) unsigned short Bs[2][256 * 64];
  const int b = blockIdx.x;                    // batch = id%8 -> XCD
  const int t0 = (blockIdx.y >> 1) * 256;      // t-tile
  const int row0 = (blockIdx.y & 1) * 256;     // M-tile
  const unsigned short* xb = xbT + (size_t)b * TT * CIN;
  const int tid = threadIdx.x;
  const int lane = tid & 63, wid = tid >> 6;
  const int wr = wid >> 2, wc = wid & 3;
  const int l15 = lane & 15, kg = lane >> 4;

  // staging sources: round j covers row r = j*64 + (tid>>3), chunk slot tid&7
  const int srow = tid >> 3;
  const int cSrc8 = (((tid & 7) ^ ((tid >> 4) & 7))) * 8;  // swizzled 16B chunk
  int aOff[4];                       // Wb ushort offsets, add tc*64
  int bOffP[4], bOffC[4], bOffF[4];  // per-segment xbT offsets (static j index)
#pragma unroll
  for (int j = 0; j < 4; ++j) {
    int r = j * 64 + srow;
    aOff[j] = (row0 + r) * KTOT + cSrc8;
    int t = t0 + r;
    float dv = d[(size_t)b * TT + t];
    int dil = (int)dv; if (dil < 1) dil = 1;
    int p = t - dil; if (p < 0) p = -p; p &= (TT - 1);
    int f0 = t + dil;
    int f = (f0 >= TT) ? (TT - 1 - (f0 & (TT - 1))) : f0;
    bOffP[j] = p * CIN + cSrc8;
    bOffC[j] = t * CIN + cSrc8;
    bOffF[j] = f * CIN + cSrc8;
  }

  // fragment read offsets (swizzled): row r, chunk (kh*4+kg) ^ ((r>>1)&7)
  const int s7 = l15 >> 1;
  const int chunk0 = (kg ^ (s7 & 3)) + (s7 & 4);
  const int dK = (l15 & 8) ? -32 : 32;  // ushort delta for kh=1
  int aRd[2][4], bRd[2][2];
#pragma unroll
  for (int mh = 0; mh < 2; ++mh)
#pragma unroll
    for (int mi = 0; mi < 4; ++mi)
      aRd[mh][mi] = (wr * 128 + mh * 64 + mi * 16 + l15) * 64 + chunk0 * 8;
#pragma unroll
  for (int nh = 0; nh < 2; ++nh)
#pragma unroll
    for (int ni = 0; ni < 2; ++ni)
      bRd[nh][ni] = (wc * 64 + nh * 32 + ni * 16 + l15) * 64 + chunk0 * 8;

#define STAGE_A_G0(tc_, buf_) do {                                            \
    GLD16(Wb + aOff[0] + (tc_) * 64, &As[buf_][0 * 4096 + wid * 512]);        \
    GLD16(Wb + aOff[2] + (tc_) * 64, &As[buf_][2 * 4096 + wid * 512]);        \
  } while (0)
#define STAGE_A_G1(tc_, buf_) do {                                            \
    GLD16(Wb + aOff[1] + (tc_) * 64, &As[buf_][1 * 4096 + wid * 512]);        \
    GLD16(Wb + aOff[3] + (tc_) * 64, &As[buf_][3 * 4096 + wid * 512]);        \
  } while (0)
// seg select: with unroll 8 the (tc)>>3 index is compile-time -> no cndmask
#define BSEL(seg_, j_) ((seg_) == 0 ? bOffP[j_] : ((seg_) == 1 ? bOffC[j_] : bOffF[j_]))
#define STAGE_B4(tc_, buf_) do {                                              \
    int seg_ = (tc_) >> 3; int k8_ = ((tc_) & 7) * 64;                        \
    _Pragma("unroll") for (int j = 0; j < 4; ++j)                             \
      GLD16(xb + BSEL(seg_, j) + k8_, &Bs[buf_][j * 4096 + wid * 512]);       \
  } while (0)

  // prologue: tile 0 fully staged; full drain once
  STAGE_B4(0, 0); STAGE_A_G0(0, 0); STAGE_A_G1(0, 0);
  VMCNT0();
  SBAR();

  bf16x8 af[4][2], bf0[2][2], bf1[2][2];
  f32x4 acc[8][4] = {};

#pragma unroll 8
  for (int tc = 0; tc < NT; ++tc) {
    const int cur = tc & 1;
    // ---------- PH0: frag reads (af mh0 first, then bf0, bf1); stage B+A-g0 (t+1)
#pragma unroll
    for (int mi = 0; mi < 4; ++mi) {
      af[mi][0] = *(const bf16x8*)&As[cur][aRd[0][mi]];
      af[mi][1] = *(const bf16x8*)&As[cur][aRd[0][mi] + dK];
    }
#pragma unroll
    for (int ni = 0; ni < 2; ++ni) {
      bf0[ni][0] = *(const bf16x8*)&Bs[cur][bRd[0][ni]];
      bf0[ni][1] = *(const bf16x8*)&Bs[cur][bRd[0][ni] + dK];
    }
#pragma unroll
    for (int ni = 0; ni < 2; ++ni) {
      bf1[ni][0] = *(const bf16x8*)&Bs[cur][bRd[1][ni]];
      bf1[ni][1] = *(const bf16x8*)&Bs[cur][bRd[1][ni] + dK];
    }
    if (tc + 1 < NT) { STAGE_B4(tc + 1, cur ^ 1); STAGE_A_G0(tc + 1, cur ^ 1); }
    __builtin_amdgcn_s_setprio(1);
#pragma unroll
    for (int mi = 0; mi < 4; ++mi)
#pragma unroll
      for (int ni = 0; ni < 2; ++ni) {
        acc[mi][ni] = MFMA(af[mi][0], bf0[ni][0], acc[mi][ni]);
        acc[mi][ni] = MFMA(af[mi][1], bf0[ni][1], acc[mi][ni]);
        acc[mi][2 + ni] = MFMA(af[mi][0], bf1[ni][0], acc[mi][2 + ni]);
        acc[mi][2 + ni] = MFMA(af[mi][1], bf1[ni][1], acc[mi][2 + ni]);
      }
    __builtin_amdgcn_s_setprio(0);
    // (no MID lgkm0: reads are MFMA-consumed; END lgkm0 fences the WAR)
    if (tc + 1 < NT) { VMCNT6(); }        // drain A-g1(t); keep PH0 stages
    else { VMCNT0(); }
    SBAR();                               // MID: publishes A-mh1(t)
    // ---------- PH2: frag reads (af mh1); stage A-g1(t+1)
#pragma unroll
    for (int mi = 0; mi < 4; ++mi) {
      af[mi][0] = *(const bf16x8*)&As[cur][aRd[1][mi]];
      af[mi][1] = *(const bf16x8*)&As[cur][aRd[1][mi] + dK];
    }
    if (tc + 1 < NT) STAGE_A_G1(tc + 1, cur ^ 1);
    __builtin_amdgcn_s_setprio(1);
#pragma unroll
    for (int mi = 0; mi < 4; ++mi)
#pragma unroll
      for (int ni = 0; ni < 2; ++ni) {
        acc[4 + mi][ni] = MFMA(af[mi][0], bf0[ni][0], acc[4 + mi][ni]);
        acc[4 + mi][ni] = MFMA(af[mi][1], bf0[ni][1], acc[4 + mi][ni]);
        acc[4 + mi][2 + ni] = MFMA(af[mi][0], bf1[ni][0], acc[4 + mi][2 + ni]);
        acc[4 + mi][2 + ni] = MFMA(af[mi][1], bf1[ni][1], acc[4 + mi][2 + ni]);
      }
    __builtin_amdgcn_s_setprio(0);
    LGKM0();                              // all [cur] reads done (WAR vs t+1 staging)
    if (tc + 1 < NT) { VMCNT2(); }        // drain B(t+1)+A-g0(t+1); keep A-g1(t+1)
    SBAR();                               // END: publishes B(t+1)+A-g0(t+1)
  }

  // epilogue: bias + fp32 store
  float* ob = out + (size_t)b * COUT * TT;
#pragma unroll
  for (int mh = 0; mh < 2; ++mh)
#pragma unroll
    for (int mi = 0; mi < 4; ++mi) {
      int m0 = row0 + wr * 128 + mh * 64 + mi * 16 + kg * 4;
#pragma unroll
      for (int nh = 0; nh < 2; ++nh)
#pragma unroll
        for (int ni = 0; ni < 2; ++ni) {
          int t = t0 + wc * 64 + nh * 32 + ni * 16 + l15;
          f32x4 v = acc[mh * 4 + mi][nh * 2 + ni];
#pragma unroll
          for (int j = 0; j < 4; ++j)
            ob[(size_t)(m0 + j) * TT + t] = v[j] + bias[m0 + j];
        }
    }
}

// ---------------- fallback 128x128 (small ws) ----------------
__global__ __launch_bounds__(256) void k_gemm(
    const unsigned short* __restrict__ Wb, const unsigned short* __restrict__ xbT,
    const float* __restrict__ d, const float* __restrict__ bias,
    float* __restrict__ out, int b_base) {
  __shared__ __align__(16) unsigned short As[128 * 32];
  __shared__ __align__(16) unsigned short Bs[128 * 32];
  int b = b_base + blockIdx.z;
  const unsigned short* xb = xbT + (size_t)blockIdx.z * TT * CIN;
  int row0 = blockIdx.x * 128;
  int t0 = blockIdx.y * 128;
  int tid = threadIdx.x;
  int lane = tid & 63, wid = tid >> 6;
  int wr = wid >> 1, wc = wid & 1;
  int l15 = lane & 15, kg = lane >> 4;
  int rs = tid >> 2, cch = tid & 3;

  const unsigned short* aw[2];
  const unsigned short* bw[2][3];
#pragma unroll
  for (int h = 0; h < 2; ++h) {
    int r = rs + h * 64;
    int cs = cch ^ ((r >> 1) & 3);
    aw[h] = Wb + (size_t)(row0 + r) * KTOT + cs * 8;
    int t = t0 + r;
    float dv = d[(size_t)b * TT + t];
    int dil = (int)dv; if (dil < 1) dil = 1;
    int p = t - dil; if (p < 0) p = -p; p &= (TT - 1);
    int f0 = t + dil;
    int f = (f0 >= TT) ? (TT - 1 - (f0 & (TT - 1))) : f0;
    bw[h][0] = xb + (size_t)p * CIN + cs * 8;
    bw[h][1] = xb + (size_t)t * CIN + cs * 8;
    bw[h][2] = xb + (size_t)f * CIN + cs * 8;
  }
  unsigned short* aDst[2];
  unsigned short* bDst[2];
#pragma unroll
  for (int h = 0; h < 2; ++h) {
    aDst[h] = As + h * 2048 + wid * 512;
    bDst[h] = Bs + h * 2048 + wid * 512;
  }
  int aoff[4], boff[4];
#pragma unroll
  for (int mi = 0; mi < 4; ++mi) {
    int r = wr * 64 + mi * 16 + l15;
    aoff[mi] = r * 32 + (kg ^ ((r >> 1) & 3)) * 8;
  }
#pragma unroll
  for (int ni = 0; ni < 4; ++ni) {
    int r = wc * 64 + ni * 16 + l15;
    boff[ni] = r * 32 + (kg ^ ((r >> 1) & 3)) * 8;
  }
  f32x4 acc[4][4] = {};
#pragma unroll
  for (int s = 0; s < 3; ++s) {
    for (int kt = 0; kt < 16; ++kt) {
      int koff = kt * 32;
#pragma unroll
      for (int h = 0; h < 2; ++h) {
        GLD16(aw[h] + s * CIN + koff, aDst[h]);
        GLD16(bw[h][s] + koff, bDst[h]);
      }
      __syncthreads();
      bf16x8 af[4], bf[4];
#pragma unroll
      for (int mi = 0; mi < 4; ++mi) af[mi] = *(const bf16x8*)(&As[aoff[mi]]);
#pragma unroll
      for (int ni = 0; ni < 4; ++ni) bf[ni] = *(const bf16x8*)(&Bs[boff[ni]]);
#pragma unroll
      for (int mi = 0; mi < 4; ++mi)
#pragma unroll
        for (int ni = 0; ni < 4; ++ni)
          acc[mi][ni] = MFMA(af[mi], bf[ni], acc[mi][ni]);
      __syncthreads();
    }
  }
  float* ob = out + (size_t)b * COUT * TT;
#pragma unroll
  for (int mi = 0; mi < 4; ++mi) {
    int m0 = row0 + wr * 64 + mi * 16 + kg * 4;
#pragma unroll
    for (int ni = 0; ni < 4; ++ni) {
      int t = t0 + wc * 64 + ni * 16 + l15;
#pragma unroll
      for (int j = 0; j < 4; ++j) {
        ob[(size_t)(m0 + j) * TT + t] = acc[mi][ni][j] + bias[m0 + j];
      }
    }
  }
}

extern "C" void kernel_launch(void* const* d_in, const int* in_sizes, int n_in,
                              void* d_out, int out_size, void* d_ws, size_t ws_size,
                              hipStream_t stream) {
  const float* x  = (const float*)d_in[0];
  const float* d  = (const float*)d_in[1];
  const float* W0 = (const float*)d_in[2];
  const float* b0 = (const float*)d_in[3];
  const float* W1 = (const float*)d_in[4];
  const float* W2 = (const float*)d_in[5];
  float* out = (float*)d_out;

  char* ws = (char*)d_ws;
  unsigned short* Wb  = (unsigned short*)ws;                       // 1.5 MiB
  unsigned short* xbT = (unsigned short*)(ws + (2u << 20));        // 8 MiB per batch
  const size_t SZ_XBT1 = (size_t)TT * CIN * 2;
  const size_t NEED_FULL = (size_t)(2u << 20) + (size_t)NB * SZ_XBT1;  // ~66 MiB
  const size_t NEED_MIN  = (size_t)(2u << 20) + SZ_XBT1;               // ~10 MiB

  if (ws_size >= NEED_MIN) {
    k_convert_w<<<dim3(1024, 3), 256, 0, stream>>>(W0, W1, W2, Wb);
    if (ws_size >= NEED_FULL) {
      k_transpose<<<dim3(TT / 64, CIN / 64, NB), 256, 0, stream>>>(x, xbT, 0);
      k_gemm256<<<dim3(NB, (TT / 256) * (COUT / 256), 1), 512, 0, stream>>>(
          Wb, xbT, d, b0, out);
    } else {
      for (int b = 0; b < NB; ++b) {
        k_transpose<<<dim3(TT / 64, CIN / 64, 1), 256, 0, stream>>>(x, xbT, b);
        k_gemm<<<dim3(COUT / 128, TT / 128, 1), 256, 0, stream>>>(Wb, xbT, d, b0, out, b);
      }
    }
  } else {
    for (int b = 0; b < NB; ++b) {
      k_transpose<<<dim3(TT / 64, CIN / 64, 1), 256, 0, stream>>>(x, xbT, b);
      k_gemm<<<dim3(COUT / 128, TT / 128, 1), 256, 0, stream>>>(Wb, xbT, d, b0, out, b);
    }
  }
}

// Round 16
// 142.013 us; speedup vs baseline: 1.2022x; 1.2022x over previous
//
#include <hip/hip_runtime.h>

#define TT 8192
#define CIN 512
#define COUT 512
#define NB 8
#define KTOT 1536   // 3 * CIN
#define NT 24       // K tiles of 64

typedef __attribute__((ext_vector_type(4))) float f32x4;
typedef __attribute__((ext_vector_type(8))) short bf16x8;
typedef __attribute__((ext_vector_type(8))) unsigned short u16x8;

#define GLD16(g, l) __builtin_amdgcn_global_load_lds(                      \
    (const __attribute__((address_space(1))) void*)(g),                    \
    (__attribute__((address_space(3))) void*)(l), 16, 0, 0)

#define CFENCE() asm volatile("" ::: "memory")
#define SBAR() do { CFENCE(); __builtin_amdgcn_s_barrier(); CFENCE(); } while (0)
#define VMCNT6() asm volatile("s_waitcnt vmcnt(6)" ::: "memory")
#define VMCNT2() asm volatile("s_waitcnt vmcnt(2)" ::: "memory")
#define VMCNT0() asm volatile("s_waitcnt vmcnt(0)" ::: "memory")
#define LGKM0() asm volatile("s_waitcnt lgkmcnt(0)" ::: "memory")
#define MFMA(a_, b_, c_) __builtin_amdgcn_mfma_f32_16x16x32_bf16((a_), (b_), (c_), 0, 0, 0)

__device__ inline unsigned short f2bf(float f) {
  union { float f; unsigned int u; } v; v.f = f;
  unsigned int u = v.u;
  unsigned int r = (u + 0x7FFFu + ((u >> 16) & 1u)) >> 16;  // RNE
  return (unsigned short)r;
}

__global__ void k_convert_w(const float* __restrict__ W0, const float* __restrict__ W1,
                            const float* __restrict__ W2, unsigned short* __restrict__ Wb) {
  int i = blockIdx.x * 256 + threadIdx.x;
  if (i >= COUT * CIN) return;
  const float* Ws = blockIdx.y == 0 ? W0 : (blockIdx.y == 1 ? W1 : W2);
  int o = i >> 9, c = i & 511;
  Wb[(size_t)o * KTOT + blockIdx.y * CIN + c] = f2bf(Ws[i]);
}

// x (B, C, T) fp32 -> xbT (T, C) bf16 per batch. grid (T/64, C/64, nb), block 256
__global__ void k_transpose(const float* __restrict__ x, unsigned short* __restrict__ xbT,
                            int b_base) {
  int b = b_base + blockIdx.z;
  const float* xb = x + (size_t)b * CIN * TT;
  unsigned short* xo = xbT + (size_t)blockIdx.z * TT * CIN;
  __shared__ float tile[64][65];
  int t0 = blockIdx.x * 64, c0 = blockIdx.y * 64;
  int tid = threadIdx.x;
#pragma unroll
  for (int it = 0; it < 16; ++it) {
    int L = it * 256 + tid;
    int c = L >> 6, t = L & 63;
    tile[c][t] = xb[(size_t)(c0 + c) * TT + (t0 + t)];
  }
  __syncthreads();
#pragma unroll
  for (int it = 0; it < 16; ++it) {
    int L = it * 256 + tid;
    int t = L >> 6, c = L & 63;
    xo[(size_t)(t0 + t) * CIN + (c0 + c)] = f2bf(tile[c][t]);
  }
}

// -------- 256x256 fused gather-GEMM, half-publish pipeline (2 barriers/tile) --------
// grid (8, 64), block 512 (8 waves, 2M x 4N). id%8 = batch -> XCD.
// Tile t: PH0{read af(mh0)+bf0+bf1; stage B(t+1)+A-g0(t+1); MFMA Q00+Q01;
//             lgkm0; vmcnt(6) [drain A-g1(t)]; BAR = publish A-mh1(t)}
//         PH2{read af(mh1); stage A-g1(t+1); MFMA Q10+Q11;
//             lgkm0; vmcnt(2) [drain B(t+1)+A-g0(t+1), keep A-g1(t+1)]; BAR}
// A-g0 = stage rounds {0,2} (rows 0-63,128-191 = both wr's mh0); A-g1 = rounds {1,3}.
__global__ __launch_bounds__(512) void k_gemm256(
    const unsigned short* __restrict__ Wb, const unsigned short* __restrict__ xbT,
    const float* __restrict__ d, const float* __restrict__ bias,
    float* __restrict__ out) {
  __shared__ __align__(16) unsigned short As[2][256 * 64];
  __shared__ __align__(16) unsigned short Bs[2][256 * 64];
  const int b = blockIdx.x;                    // batch = id%8 -> XCD
  const int t0 = (blockIdx.y >> 1) * 256;      // t-tile
  const int row0 = (blockIdx.y & 1) * 256;     // M-tile
  const unsigned short* xb = xbT + (size_t)b * TT * CIN;
  const int tid = threadIdx.x;
  const int lane = tid & 63, wid = tid >> 6;
  const int wr = wid >> 2, wc = wid & 3;
  const int l15 = lane & 15, kg = lane >> 4;

  // staging sources: round j covers row r = j*64 + (tid>>3), chunk slot tid&7
  const int srow = tid >> 3;
  const int cSrc8 = (((tid & 7) ^ ((tid >> 4) & 7))) * 8;  // swizzled 16B chunk
  int aOff[4];        // Wb ushort offsets, add tc*64
  int bOff[3][4];     // xbT ushort offsets per segment, add (tc&7)*64
#pragma unroll
  for (int j = 0; j < 4; ++j) {
    int r = j * 64 + srow;
    aOff[j] = (row0 + r) * KTOT + cSrc8;
    int t = t0 + r;
    float dv = d[(size_t)b * TT + t];
    int dil = (int)dv; if (dil < 1) dil = 1;
    int p = t - dil; if (p < 0) p = -p; p &= (TT - 1);
    int f0 = t + dil;
    int f = (f0 >= TT) ? (TT - 1 - (f0 & (TT - 1))) : f0;
    bOff[0][j] = p * CIN + cSrc8;
    bOff[1][j] = t * CIN + cSrc8;
    bOff[2][j] = f * CIN + cSrc8;
  }

  // fragment read offsets (swizzled): row r, chunk (kh*4+kg) ^ ((r>>1)&7)
  const int s7 = l15 >> 1;
  const int chunk0 = (kg ^ (s7 & 3)) + (s7 & 4);
  const int dK = (l15 & 8) ? -32 : 32;  // ushort delta for kh=1
  int aRd[2][4], bRd[2][2];
#pragma unroll
  for (int mh = 0; mh < 2; ++mh)
#pragma unroll
    for (int mi = 0; mi < 4; ++mi)
      aRd[mh][mi] = (wr * 128 + mh * 64 + mi * 16 + l15) * 64 + chunk0 * 8;
#pragma unroll
  for (int nh = 0; nh < 2; ++nh)
#pragma unroll
    for (int ni = 0; ni < 2; ++ni)
      bRd[nh][ni] = (wc * 64 + nh * 32 + ni * 16 + l15) * 64 + chunk0 * 8;

#define STAGE_A_G0(tc_, buf_) do {                                            \
    GLD16(Wb + aOff[0] + (tc_) * 64, &As[buf_][0 * 4096 + wid * 512]);        \
    GLD16(Wb + aOff[2] + (tc_) * 64, &As[buf_][2 * 4096 + wid * 512]);        \
  } while (0)
#define STAGE_A_G1(tc_, buf_) do {                                            \
    GLD16(Wb + aOff[1] + (tc_) * 64, &As[buf_][1 * 4096 + wid * 512]);        \
    GLD16(Wb + aOff[3] + (tc_) * 64, &As[buf_][3 * 4096 + wid * 512]);        \
  } while (0)
#define STAGE_B4(tc_, buf_) do {                                              \
    _Pragma("unroll") for (int j = 0; j < 4; ++j)                             \
      GLD16(xb + bOff[(tc_) >> 3][j] + ((tc_) & 7) * 64,                      \
            &Bs[buf_][j * 4096 + wid * 512]);                                 \
  } while (0)

  // prologue: tile 0 fully staged; full drain once; steady state starts at tc=0
  STAGE_B4(0, 0); STAGE_A_G0(0, 0); STAGE_A_G1(0, 0);
  VMCNT0();
  SBAR();

  bf16x8 af[4][2], bf0[2][2], bf1[2][2];
  f32x4 acc[8][4] = {};

#pragma unroll 2
  for (int tc = 0; tc < NT; ++tc) {
    const int cur = tc & 1;
    // ---------- PH0: frag reads (af mh0, bf both halves); stage B+A-g0 (t+1)
#pragma unroll
    for (int mi = 0; mi < 4; ++mi) {
      af[mi][0] = *(const bf16x8*)&As[cur][aRd[0][mi]];
      af[mi][1] = *(const bf16x8*)&As[cur][aRd[0][mi] + dK];
    }
#pragma unroll
    for (int ni = 0; ni < 2; ++ni) {
      bf0[ni][0] = *(const bf16x8*)&Bs[cur][bRd[0][ni]];
      bf0[ni][1] = *(const bf16x8*)&Bs[cur][bRd[0][ni] + dK];
      bf1[ni][0] = *(const bf16x8*)&Bs[cur][bRd[1][ni]];
      bf1[ni][1] = *(const bf16x8*)&Bs[cur][bRd[1][ni] + dK];
    }
    if (tc + 1 < NT) { STAGE_B4(tc + 1, cur ^ 1); STAGE_A_G0(tc + 1, cur ^ 1); }
    __builtin_amdgcn_s_setprio(1);
#pragma unroll
    for (int mi = 0; mi < 4; ++mi)
#pragma unroll
      for (int ni = 0; ni < 2; ++ni) {
        acc[mi][ni] = MFMA(af[mi][0], bf0[ni][0], acc[mi][ni]);
        acc[mi][ni] = MFMA(af[mi][1], bf0[ni][1], acc[mi][ni]);
        acc[mi][2 + ni] = MFMA(af[mi][0], bf1[ni][0], acc[mi][2 + ni]);
        acc[mi][2 + ni] = MFMA(af[mi][1], bf1[ni][1], acc[mi][2 + ni]);
      }
    __builtin_amdgcn_s_setprio(0);
    LGKM0();                              // own af(mh0)+bf reads done
    if (tc + 1 < NT) { VMCNT6(); }        // drain A-g1(t); keep PH0 stages
    else { VMCNT0(); }
    SBAR();                               // MID: publishes A-mh1(t)
    // ---------- PH2: frag reads (af mh1); stage A-g1(t+1)
#pragma unroll
    for (int mi = 0; mi < 4; ++mi) {
      af[mi][0] = *(const bf16x8*)&As[cur][aRd[1][mi]];
      af[mi][1] = *(const bf16x8*)&As[cur][aRd[1][mi] + dK];
    }
    if (tc + 1 < NT) STAGE_A_G1(tc + 1, cur ^ 1);
    __builtin_amdgcn_s_setprio(1);
#pragma unroll
    for (int mi = 0; mi < 4; ++mi)
#pragma unroll
      for (int ni = 0; ni < 2; ++ni) {
        acc[4 + mi][ni] = MFMA(af[mi][0], bf0[ni][0], acc[4 + mi][ni]);
        acc[4 + mi][ni] = MFMA(af[mi][1], bf0[ni][1], acc[4 + mi][ni]);
        acc[4 + mi][2 + ni] = MFMA(af[mi][0], bf1[ni][0], acc[4 + mi][2 + ni]);
        acc[4 + mi][2 + ni] = MFMA(af[mi][1], bf1[ni][1], acc[4 + mi][2 + ni]);
      }
    __builtin_amdgcn_s_setprio(0);
    LGKM0();                              // own af(mh1) reads done (WAR vs t+1 writes)
    if (tc + 1 < NT) { VMCNT2(); }        // drain B(t+1)+A-g0(t+1); keep A-g1(t+1)
    SBAR();                               // END: publishes B(t+1)+A-g0(t+1)
  }

  // epilogue: bias + fp32 store
  float* ob = out + (size_t)b * COUT * TT;
#pragma unroll
  for (int mh = 0; mh < 2; ++mh)
#pragma unroll
    for (int mi = 0; mi < 4; ++mi) {
      int m0 = row0 + wr * 128 + mh * 64 + mi * 16 + kg * 4;
#pragma unroll
      for (int nh = 0; nh < 2; ++nh)
#pragma unroll
        for (int ni = 0; ni < 2; ++ni) {
          int t = t0 + wc * 64 + nh * 32 + ni * 16 + l15;
          f32x4 v = acc[mh * 4 + mi][nh * 2 + ni];
#pragma unroll
          for (int j = 0; j < 4; ++j)
            ob[(size_t)(m0 + j) * TT + t] = v[j] + bias[m0 + j];
        }
    }
}

// ---------------- fallback 128x128 (small ws) ----------------
__global__ __launch_bounds__(256) void k_gemm(
    const unsigned short* __restrict__ Wb, const unsigned short* __restrict__ xbT,
    const float* __restrict__ d, const float* __restrict__ bias,
    float* __restrict__ out, int b_base) {
  __shared__ __align__(16) unsigned short As[128 * 32];
  __shared__ __align__(16) unsigned short Bs[128 * 32];
  int b = b_base + blockIdx.z;
  const unsigned short* xb = xbT + (size_t)blockIdx.z * TT * CIN;
  int row0 = blockIdx.x * 128;
  int t0 = blockIdx.y * 128;
  int tid = threadIdx.x;
  int lane = tid & 63, wid = tid >> 6;
  int wr = wid >> 1, wc = wid & 1;
  int l15 = lane & 15, kg = lane >> 4;
  int rs = tid >> 2, cch = tid & 3;

  const unsigned short* aw[2];
  const unsigned short* bw[2][3];
#pragma unroll
  for (int h = 0; h < 2; ++h) {
    int r = rs + h * 64;
    int cs = cch ^ ((r >> 1) & 3);
    aw[h] = Wb + (size_t)(row0 + r) * KTOT + cs * 8;
    int t = t0 + r;
    float dv = d[(size_t)b * TT + t];
    int dil = (int)dv; if (dil < 1) dil = 1;
    int p = t - dil; if (p < 0) p = -p; p &= (TT - 1);
    int f0 = t + dil;
    int f = (f0 >= TT) ? (TT - 1 - (f0 & (TT - 1))) : f0;
    bw[h][0] = xb + (size_t)p * CIN + cs * 8;
    bw[h][1] = xb + (size_t)t * CIN + cs * 8;
    bw[h][2] = xb + (size_t)f * CIN + cs * 8;
  }
  unsigned short* aDst[2];
  unsigned short* bDst[2];
#pragma unroll
  for (int h = 0; h < 2; ++h) {
    aDst[h] = As + h * 2048 + wid * 512;
    bDst[h] = Bs + h * 2048 + wid * 512;
  }
  int aoff[4], boff[4];
#pragma unroll
  for (int mi = 0; mi < 4; ++mi) {
    int r = wr * 64 + mi * 16 + l15;
    aoff[mi] = r * 32 + (kg ^ ((r >> 1) & 3)) * 8;
  }
#pragma unroll
  for (int ni = 0; ni < 4; ++ni) {
    int r = wc * 64 + ni * 16 + l15;
    boff[ni] = r * 32 + (kg ^ ((r >> 1) & 3)) * 8;
  }
  f32x4 acc[4][4] = {};
#pragma unroll
  for (int s = 0; s < 3; ++s) {
    for (int kt = 0; kt < 16; ++kt) {
      int koff = kt * 32;
#pragma unroll
      for (int h = 0; h < 2; ++h) {
        GLD16(aw[h] + s * CIN + koff, aDst[h]);
        GLD16(bw[h][s] + koff, bDst[h]);
      }
      __syncthreads();
      bf16x8 af[4], bf[4];
#pragma unroll
      for (int mi = 0; mi < 4; ++mi) af[mi] = *(const bf16x8*)(&As[aoff[mi]]);
#pragma unroll
      for (int ni = 0; ni < 4; ++ni) bf[ni] = *(const bf16x8*)(&Bs[boff[ni]]);
#pragma unroll
      for (int mi = 0; mi < 4; ++mi)
#pragma unroll
        for (int ni = 0; ni < 4; ++ni)
          acc[mi][ni] = MFMA(af[mi], bf[ni], acc[mi][ni]);
      __syncthreads();
    }
  }
  float* ob = out + (size_t)b * COUT * TT;
#pragma unroll
  for (int mi = 0; mi < 4; ++mi) {
    int m0 = row0 + wr * 64 + mi * 16 + kg * 4;
#pragma unroll
    for (int ni = 0; ni < 4; ++ni) {
      int t = t0 + wc * 64 + ni * 16 + l15;
#pragma unroll
      for (int j = 0; j < 4; ++j) {
        ob[(size_t)(m0 + j) * TT + t] = acc[mi][ni][j] + bias[m0 + j];
      }
    }
  }
}

extern "C" void kernel_launch(void* const* d_in, const int* in_sizes, int n_in,
                              void* d_out, int out_size, void* d_ws, size_t ws_size,
                              hipStream_t stream) {
  const float* x  = (const float*)d_in[0];
  const float* d  = (const float*)d_in[1];
  const float* W0 = (const float*)d_in[2];
  const float* b0 = (const float*)d_in[3];
  const float* W1 = (const float*)d_in[4];
  const float* W2 = (const float*)d_in[5];
  float* out = (float*)d_out;

  char* ws = (char*)d_ws;
  unsigned short* Wb  = (unsigned short*)ws;                       // 1.5 MiB
  unsigned short* xbT = (unsigned short*)(ws + (2u << 20));        // 8 MiB per batch
  const size_t SZ_XBT1 = (size_t)TT * CIN * 2;
  const size_t NEED_FULL = (size_t)(2u << 20) + (size_t)NB * SZ_XBT1;  // ~66 MiB
  const size_t NEED_MIN  = (size_t)(2u << 20) + SZ_XBT1;               // ~10 MiB

  if (ws_size >= NEED_MIN) {
    k_convert_w<<<dim3(1024, 3), 256, 0, stream>>>(W0, W1, W2, Wb);
    if (ws_size >= NEED_FULL) {
      k_transpose<<<dim3(TT / 64, CIN / 64, NB), 256, 0, stream>>>(x, xbT, 0);
      k_gemm256<<<dim3(NB, (TT / 256) * (COUT / 256), 1), 512, 0, stream>>>(
          Wb, xbT, d, b0, out);
    } else {
      for (int b = 0; b < NB; ++b) {
        k_transpose<<<dim3(TT / 64, CIN / 64, 1), 256, 0, stream>>>(x, xbT, b);
        k_gemm<<<dim3(COUT / 128, TT / 128, 1), 256, 0, stream>>>(Wb, xbT, d, b0, out, b);
      }
    }
  } else {
    for (int b = 0; b < NB; ++b) {
      k_transpose<<<dim3(TT / 64, CIN / 64, 1), 256, 0, stream>>>(x, xbT, b);
      k_gemm<<<dim3(COUT / 128, TT / 128, 1), 256, 0, stream>>>(Wb, xbT, d, b0, out, b);
    }
  }
}